// Round 3
// baseline (491.405 us; speedup 1.0000x reference)
//
#include <hip/hip_runtime.h>
#include <hip/hip_cooperative_groups.h>

namespace cg = cooperative_groups;

// Problem constants (fixed by the reference file)
#define BATCH   8
#define NVERT   50000
#define CIN     32
#define LSP     9
#define COUT    64
#define MVERT   12500
#define NNZ     37500

#define NFRAG   2304           // 9 s * 4 g * 64 lanes (B fragments)
#define OUTDW   (BATCH * MVERT * COUT)

#define TILE_T  128            // tasks per block (32 per wave, 2 M-tiles)
#define TPB     293            // ceil(37500/128)

#define SETUP_BLOCKS 512
#define SETUP_THREADS (SETUP_BLOCKS * 256)    // 131072
#define SCAN_BLOCKS 49                        // 49*256 = 12544 >= MVERT

typedef __attribute__((ext_vector_type(8))) short  short8;
typedef __attribute__((ext_vector_type(4))) float  floatx4;

static __device__ __forceinline__ unsigned short f2bf(float f) {
    union { float f; unsigned int u; } c; c.f = f;
    unsigned int u = c.u;
    return (unsigned short)((u + 0x7fffu + ((u >> 16) & 1u)) >> 16);
}

// scan partials live in device globals (no ws-layout change, no races)
__device__ int g_bsum[64];
__device__ int g_bsumP[64];

// ---- k1 (cooperative): precast x | pack W | zero out/hist | hist | scan |
// scatter.  Replaces memset+prep+hist+scan+scatter (5 dispatch boundaries)
// with one launch and 5 grid.sync()s; scan is two-level parallel instead of
// one 1024-thread block.
__global__ __launch_bounds__(256)
void setup_kernel(const float* __restrict__ x, const float* __restrict__ w,
                  const int* __restrict__ rows, const int* __restrict__ cols,
                  const float* __restrict__ vals, const int* __restrict__ spiral,
                  unsigned short* __restrict__ x16, unsigned short* __restrict__ wp,
                  float* __restrict__ out, int* __restrict__ hist,
                  int* __restrict__ off2,
                  int* __restrict__ rows_s, float* __restrict__ vals_s,
                  unsigned short* __restrict__ tidx)
{
    cg::grid_group grid = cg::this_grid();
    const int blk = blockIdx.x;
    const int tid = threadIdx.x;
    const int gid = blk * 256 + tid;

    // ---- phase A: precast x -> bf16, pack W, zero out, zero hist
    for (int v = gid; v < 1600000; v += SETUP_THREADS) {     // 12.8M f32 / 8
        const size_t base = (size_t)v * 8;
        const float4* s = (const float4*)(x + base);
        float4 a = s[0], c = s[1];
        unsigned short t[8];
        t[0]=f2bf(a.x); t[1]=f2bf(a.y); t[2]=f2bf(a.z); t[3]=f2bf(a.w);
        t[4]=f2bf(c.x); t[5]=f2bf(c.y); t[6]=f2bf(c.z); t[7]=f2bf(c.w);
        *(uint4*)(x16 + base) = *(uint4*)t;
    }
    for (int v = gid; v < OUTDW / 4; v += SETUP_THREADS)     // zero out (12.8 MB)
        *(uint4*)(out + (size_t)v * 4) = (uint4){0, 0, 0, 0};
    if (gid < NFRAG) {
        // B-frag f=(s*4+g)*64+lane holds W[s*32+(lane>>4)*8+j][g*16+(lane&15)]
        const int f = gid;
        int s = f >> 8, g = (f >> 6) & 3, lane = f & 63;
        int k0 = s * 32 + (lane >> 4) * 8, col = g * 16 + (lane & 15);
        unsigned short t[8];
        #pragma unroll
        for (int j = 0; j < 8; ++j)
            t[j] = f2bf(w[(size_t)(k0 + j) * COUT + col]);
        ((uint4*)wp)[f] = *(uint4*)t;
    }
    if (gid < MVERT) hist[gid] = 0;

    grid.sync();

    // ---- phase B: histogram of rows
    if (gid < NNZ) atomicAdd(&hist[rows[gid]], 1);

    grid.sync();

    // ---- phase C1: per-block scan of 256 hist entries
    __shared__ int sh[256];
    if (blk < SCAN_BLOCKS) {
        const int i = blk * 256 + tid;
        const int v = (i < MVERT) ? hist[i] : 0;
        sh[tid] = v;
        __syncthreads();
        #pragma unroll
        for (int d = 1; d < 256; d <<= 1) {
            int u = (tid >= d) ? sh[tid - d] : 0;
            __syncthreads();
            sh[tid] += u;
            __syncthreads();
        }
        const int incl = sh[tid];
        if (i < MVERT) off2[i] = incl - v;      // local exclusive
        if (tid == 255) g_bsum[blk] = incl;
    }

    grid.sync();

    // ---- phase C2: scan the 49 block sums (serial, trivial)
    if (blk == 0 && tid == 0) {
        int run = 0;
        for (int k = 0; k < SCAN_BLOCKS; ++k) {
            int t = g_bsum[k];
            g_bsumP[k] = run;
            run += t;
        }
    }

    grid.sync();

    // ---- phase C3: add block prefix
    if (blk < SCAN_BLOCKS) {
        const int i = blk * 256 + tid;
        if (i < MVERT) off2[i] += g_bsumP[blk];
    }

    grid.sync();

    // ---- phase D: scatter into row-sorted order + packed spiral indices
    if (gid < NNZ) {
        const int z = gid;
        int r = rows[z];
        int c = cols[z];
        int pos = atomicAdd(&off2[r], 1);
        rows_s[pos] = r;
        vals_s[pos] = vals[z];
        unsigned short t[16];
        #pragma unroll
        for (int s = 0; s < 9; ++s) t[s] = (unsigned short)spiral[c * LSP + s];
        #pragma unroll
        for (int s = 9; s < 16; ++s) t[s] = 0;
        uint4* dst = (uint4*)(tidx + (size_t)pos * 16);
        dst[0] = *(uint4*)t;
        dst[1] = *(uint4*)(t + 8);
    }
}

// ---- k2: fused gather+GEMM+ELU+scale + register-aggregated scatter-add
// EXACT round-0 version (fastest measured: 54 µs). 32 tasks/wave, all 18
// A-gathers issued up front, B-frags from global (L1/L2-resident 36 KB),
// zero LDS, zero barriers, run-compressed fire-and-forget atomics.
__global__ __launch_bounds__(256, 3)
void spiral_mfma6_kernel(const unsigned short* __restrict__ x16,
                         const unsigned short* __restrict__ wp,
                         const float* __restrict__ bias,
                         const unsigned short* __restrict__ tidx,
                         const int* __restrict__ rows_s,
                         const float* __restrict__ vals_s,
                         float* __restrict__ out)
{
    const int bid  = blockIdx.x;
    const int b    = bid & 7;          // XCD swizzle: batch <-> XCD (x16/out L2-local)
    const int tile = bid >> 3;
    const int tid  = threadIdx.x;
    const int w    = tid >> 6;
    const int lane = tid & 63;
    const int quad = lane >> 4;
    const int m16  = lane & 15;
    const int z0w  = tile * TILE_T + 32 * w;   // wave's first sorted-task index

    // per-lane task metadata: lane L carries task z0w + (L&31) (coalesced)
    const int   zc   = min(z0w + (lane & 31), NNZ - 1);
    const int   rowv = rows_s[zc];
    const float valv = vals_s[zc];
    const uint4 p0 = *(const uint4*)(tidx + (size_t)zc * 16);
    const unsigned int p1 = *(const unsigned int*)(tidx + (size_t)zc * 16 + 8);
    int idx[9];
    idx[0] = p0.x & 0xffff;  idx[1] = p0.x >> 16;
    idx[2] = p0.y & 0xffff;  idx[3] = p0.y >> 16;
    idx[4] = p0.z & 0xffff;  idx[5] = p0.z >> 16;
    idx[6] = p0.w & 0xffff;  idx[7] = p0.w >> 16;
    idx[8] = p1 & 0xffff;

    const unsigned short* xb = x16 + (size_t)b * NVERT * CIN;

    // ---- all A-fragment gathers up front: one latency round-trip
    short8 A[2][9];
    #pragma unroll
    for (int s = 0; s < 9; ++s) {
        #pragma unroll
        for (int mt = 0; mt < 2; ++mt) {
            int tix = __shfl(idx[s], mt * 16 + m16);
            A[mt][s] = *(const short8*)(xb + (size_t)tix * CIN + quad * 8);
        }
    }

    floatx4 acc[2][4];
    #pragma unroll
    for (int mt = 0; mt < 2; ++mt)
        #pragma unroll
        for (int g = 0; g < 4; ++g) acc[mt][g] = (floatx4){0.f, 0.f, 0.f, 0.f};

    #pragma unroll
    for (int s = 0; s < 9; ++s) {
        short8 bf[4];
        #pragma unroll
        for (int g = 0; g < 4; ++g)
            bf[g] = *(const short8*)(wp + (size_t)((s * 4 + g) * 64 + lane) * 8);
        #pragma unroll
        for (int mt = 0; mt < 2; ++mt)
            #pragma unroll
            for (int g = 0; g < 4; ++g)
                acc[mt][g] = __builtin_amdgcn_mfma_f32_16x16x32_bf16(A[mt][s], bf[g], acc[mt][g], 0, 0, 0);
    }

    // ---- epilogue: register run-compression over 4 consecutive sorted tasks
    float bs[4];
    #pragma unroll
    for (int g = 0; g < 4; ++g) bs[g] = bias[g * 16 + m16];
    float* outb = out + (size_t)b * MVERT * COUT;

    #pragma unroll
    for (int mt = 0; mt < 2; ++mt) {
        int   rr[4]; float vv[4]; bool val[4];
        #pragma unroll
        for (int r = 0; r < 4; ++r) {
            const int tsk = mt * 16 + quad * 4 + r;        // C row = quad*4 + reg
            rr[r]  = __shfl(rowv, tsk);
            vv[r]  = __shfl(valv, tsk);
            val[r] = (z0w + tsk) < NNZ;
        }
        bool emit[4];   // last element of an equal-row run
        #pragma unroll
        for (int r = 0; r < 4; ++r)
            emit[r] = (r == 3) || (!val[r + 1 > 3 ? 3 : r + 1]) || (rr[r + 1 > 3 ? 3 : r + 1] != rr[r]);
        #pragma unroll
        for (int g = 0; g < 4; ++g) {
            const int ch = g * 16 + m16;
            float s = 0.0f;
            #pragma unroll
            for (int r = 0; r < 4; ++r) {
                if (val[r]) {
                    float y = acc[mt][g][r] + bs[g];
                    y = (y > 0.0f) ? y : (__expf(y) - 1.0f);
                    s += y * vv[r];
                    if (emit[r]) {
                        atomicAdd(outb + (size_t)rr[r] * COUT + ch, s);
                        s = 0.0f;
                    }
                }
            }
        }
    }
}

extern "C" void kernel_launch(void* const* d_in, const int* in_sizes, int n_in,
                              void* d_out, int out_size, void* d_ws, size_t ws_size,
                              hipStream_t stream) {
    const float* x      = (const float*)d_in[0];
    const float* w      = (const float*)d_in[1];
    const float* bias   = (const float*)d_in[2];
    const float* vals   = (const float*)d_in[3];
    const int*   spiral = (const int*)d_in[4];
    const int*   rows   = (const int*)d_in[5];
    const int*   cols   = (const int*)d_in[6];
    float* out = (float*)d_out;

    // ws layout
    char* base = (char*)d_ws;
    unsigned short* wp     = (unsigned short*)(base);                    //    36,864 B
    unsigned short* x16    = (unsigned short*)(base + 36864);            // 25,600,000 B
    int*            hist   = (int*)(base + 25636864);
    int*            off2   = (int*)(base + 25686864);
    int*            rows_s = (int*)(base + 25736864);
    float*          vals_s = (float*)(base + 26036896);
    unsigned short* tidx   = (unsigned short*)(base + 26186912);         //  1,200,000 B

    void* args[] = {
        (void*)&x, (void*)&w, (void*)&rows, (void*)&cols, (void*)&vals,
        (void*)&spiral, (void*)&x16, (void*)&wp, (void*)&out, (void*)&hist,
        (void*)&off2, (void*)&rows_s, (void*)&vals_s, (void*)&tidx
    };
    hipLaunchCooperativeKernel((void*)setup_kernel, dim3(SETUP_BLOCKS),
                               dim3(256), args, 0, stream);

    spiral_mfma6_kernel<<<BATCH * TPB, 256, 0, stream>>>(x16, wp, bias, tidx,
                                                         rows_s, vals_s, out);
}

// Round 4
// 187.238 us; speedup vs baseline: 2.6245x; 2.6245x over previous
//
#include <hip/hip_runtime.h>

// Problem constants (fixed by the reference file)
#define BATCH   8
#define NVERT   50000
#define CIN     32
#define LSP     9
#define COUT    64
#define MVERT   12500
#define NNZ     37500

#define NFRAG   2304           // 9 s * 4 g * 64 lanes (B fragments)
#define OUTDW   (BATCH * MVERT * COUT)

#define TILE_T  128            // tasks per block (32 per wave, 2 M-tiles)
#define TPB     293            // ceil(37500/128)

#define PRE_BLOCKS   6250
#define PACK_BLOCKS  9
#define ZERO_BLOCKS  6250

#define SORT_BLOCKS  49
#define SORT_THREADS (SORT_BLOCKS * 256)   // 12544 >= MVERT

typedef __attribute__((ext_vector_type(8))) short  short8;
typedef __attribute__((ext_vector_type(4))) float  floatx4;

static __device__ __forceinline__ unsigned short f2bf(float f) {
    union { float f; unsigned int u; } c; c.f = f;
    unsigned int u = c.u;
    return (unsigned short)((u + 0x7fffu + ((u >> 16) & 1u)) >> 16);
}

// scan partials (device globals; rewritten every replay before use)
__device__ int g_bsum[64];
__device__ int g_bsumP[64];

// ---- k1: precast x | pack W | zero out (+ zero barrier counter)
__global__ __launch_bounds__(256)
void prep_kernel(const float* __restrict__ x, const float* __restrict__ w,
                 unsigned short* __restrict__ x16, unsigned short* __restrict__ wp,
                 float* __restrict__ out, int* __restrict__ barcnt)
{
    const int blk = blockIdx.x;
    const int tid = threadIdx.x;
    if (blk < PRE_BLOCKS) {
        const size_t base = ((size_t)blk * 256 + tid) * 8;
        const float4* s = (const float4*)(x + base);
        float4 a = s[0], c = s[1];
        unsigned short t[8];
        t[0]=f2bf(a.x); t[1]=f2bf(a.y); t[2]=f2bf(a.z); t[3]=f2bf(a.w);
        t[4]=f2bf(c.x); t[5]=f2bf(c.y); t[6]=f2bf(c.z); t[7]=f2bf(c.w);
        *(uint4*)(x16 + base) = *(uint4*)t;
    } else if (blk < PRE_BLOCKS + PACK_BLOCKS) {
        // B-frag f=(s*4+g)*64+lane holds W[s*32+(lane>>4)*8+j][g*16+(lane&15)]
        const int f = (blk - PRE_BLOCKS) * 256 + tid;
        if (f < NFRAG) {
            int s = f >> 8, g = (f >> 6) & 3, lane = f & 63;
            int k0 = s * 32 + (lane >> 4) * 8, col = g * 16 + (lane & 15);
            unsigned short t[8];
            #pragma unroll
            for (int j = 0; j < 8; ++j)
                t[j] = f2bf(w[(size_t)(k0 + j) * COUT + col]);
            ((uint4*)wp)[f] = *(uint4*)t;
        }
    } else {
        if (blk == PRE_BLOCKS + PACK_BLOCKS && tid == 0) *barcnt = 0;
        const size_t base = ((size_t)(blk - PRE_BLOCKS - PACK_BLOCKS) * 256 + tid) * 4;
        if (base < OUTDW) *(uint4*)(out + base) = (uint4){0, 0, 0, 0};
    }
}

// software global barrier: 49 co-resident blocks, agent-scope acq/rel so
// plain stores made before the barrier are visible across XCDs after it
// (per-XCD L2s are not coherent; release flushes, acquire invalidates).
static __device__ __forceinline__ void gbar(int* cnt, int target) {
    __syncthreads();
    if (threadIdx.x == 0) {
        __hip_atomic_fetch_add(cnt, 1, __ATOMIC_RELEASE, __HIP_MEMORY_SCOPE_AGENT);
        while (__hip_atomic_load(cnt, __ATOMIC_ACQUIRE, __HIP_MEMORY_SCOPE_AGENT) < target)
            __builtin_amdgcn_s_sleep(2);
    }
    __syncthreads();
}

// ---- k2: fused hist + two-level scan + scatter (replaces memset+hist+scan+
// scatter = 3 dispatch boundaries and a device-serializing 1-block scan).
// 49 blocks of 256 threads: trivially co-resident, deadlock-free.
__global__ __launch_bounds__(256)
void sort_kernel(const int* __restrict__ rows, const int* __restrict__ cols,
                 const float* __restrict__ vals, const int* __restrict__ spiral,
                 int* __restrict__ hist, int* __restrict__ off2,
                 int* __restrict__ rows_s, float* __restrict__ vals_s,
                 unsigned short* __restrict__ tidx, int* __restrict__ barcnt)
{
    const int blk = blockIdx.x;
    const int tid = threadIdx.x;
    const int gid = blk * 256 + tid;

    // phase 0: zero hist
    if (gid < MVERT) hist[gid] = 0;
    gbar(barcnt, 1 * SORT_BLOCKS);

    // phase 1: histogram of rows
    for (int z = gid; z < NNZ; z += SORT_THREADS)
        atomicAdd(&hist[rows[z]], 1);
    gbar(barcnt, 2 * SORT_BLOCKS);

    // phase 2: block-local scan of 256 hist entries
    __shared__ int sh[256];
    {
        const int v = (gid < MVERT) ? hist[gid] : 0;
        sh[tid] = v;
        __syncthreads();
        #pragma unroll
        for (int d = 1; d < 256; d <<= 1) {
            int u = (tid >= d) ? sh[tid - d] : 0;
            __syncthreads();
            sh[tid] += u;
            __syncthreads();
        }
        const int incl = sh[tid];
        if (gid < MVERT) off2[gid] = incl - v;      // local exclusive
        if (tid == 255) g_bsum[blk] = incl;
    }
    gbar(barcnt, 3 * SORT_BLOCKS);

    // phase 3: scan the 49 block sums (serial, trivial)
    if (blk == 0 && tid == 0) {
        int run = 0;
        for (int k = 0; k < SORT_BLOCKS; ++k) {
            int t = g_bsum[k];
            g_bsumP[k] = run;
            run += t;
        }
    }
    gbar(barcnt, 4 * SORT_BLOCKS);

    // phase 4: add block prefix
    if (gid < MVERT) off2[gid] += g_bsumP[blk];
    gbar(barcnt, 5 * SORT_BLOCKS);

    // phase 5: scatter into row-sorted order + packed per-task spiral indices
    for (int z = gid; z < NNZ; z += SORT_THREADS) {
        int r = rows[z];
        int c = cols[z];
        int pos = atomicAdd(&off2[r], 1);
        rows_s[pos] = r;
        vals_s[pos] = vals[z];
        unsigned short t[16];
        #pragma unroll
        for (int s = 0; s < 9; ++s) t[s] = (unsigned short)spiral[c * LSP + s];
        #pragma unroll
        for (int s = 9; s < 16; ++s) t[s] = 0;
        uint4* dst = (uint4*)(tidx + (size_t)pos * 16);
        dst[0] = *(uint4*)t;
        dst[1] = *(uint4*)(t + 8);
    }
}

// ---- k3: fused gather+GEMM+ELU+scale + register-aggregated scatter-add.
// Identical to the fastest measured version (54 µs) except launch_bounds
// (256,3)->(256,4): at (256,3) the compiler allocated ~148 total regs/wave
// (44 arch + ~104 acc stash for A[2][9]+acc), capping residency at 3
// waves/SIMD = 38% occupancy. (256,4) targets <=128 regs -> 4 waves/SIMD
// while still keeping ~16 of 18 gathers in flight. Kernel is latency-bound
// (all pipes <15%), so resident-wave count is the lever.
__global__ __launch_bounds__(256, 4)
void spiral_mfma9_kernel(const unsigned short* __restrict__ x16,
                         const unsigned short* __restrict__ wp,
                         const float* __restrict__ bias,
                         const unsigned short* __restrict__ tidx,
                         const int* __restrict__ rows_s,
                         const float* __restrict__ vals_s,
                         float* __restrict__ out)
{
    const int bid  = blockIdx.x;
    const int b    = bid & 7;          // XCD swizzle: batch <-> XCD (x16/out L2-local)
    const int tile = bid >> 3;
    const int tid  = threadIdx.x;
    const int w    = tid >> 6;
    const int lane = tid & 63;
    const int quad = lane >> 4;
    const int m16  = lane & 15;
    const int z0w  = tile * TILE_T + 32 * w;   // wave's first sorted-task index

    // per-lane task metadata: lane L carries task z0w + (L&31) (coalesced)
    const int   zc   = min(z0w + (lane & 31), NNZ - 1);
    const int   rowv = rows_s[zc];
    const float valv = vals_s[zc];
    const uint4 p0 = *(const uint4*)(tidx + (size_t)zc * 16);
    const unsigned int p1 = *(const unsigned int*)(tidx + (size_t)zc * 16 + 8);
    int idx[9];
    idx[0] = p0.x & 0xffff;  idx[1] = p0.x >> 16;
    idx[2] = p0.y & 0xffff;  idx[3] = p0.y >> 16;
    idx[4] = p0.z & 0xffff;  idx[5] = p0.z >> 16;
    idx[6] = p0.w & 0xffff;  idx[7] = p0.w >> 16;
    idx[8] = p1 & 0xffff;

    const unsigned short* xb = x16 + (size_t)b * NVERT * CIN;

    // ---- all A-fragment gathers up front: one latency round-trip
    short8 A[2][9];
    #pragma unroll
    for (int s = 0; s < 9; ++s) {
        #pragma unroll
        for (int mt = 0; mt < 2; ++mt) {
            int tix = __shfl(idx[s], mt * 16 + m16);
            A[mt][s] = *(const short8*)(xb + (size_t)tix * CIN + quad * 8);
        }
    }

    floatx4 acc[2][4];
    #pragma unroll
    for (int mt = 0; mt < 2; ++mt)
        #pragma unroll
        for (int g = 0; g < 4; ++g) acc[mt][g] = (floatx4){0.f, 0.f, 0.f, 0.f};

    #pragma unroll
    for (int s = 0; s < 9; ++s) {
        short8 bf[4];
        #pragma unroll
        for (int g = 0; g < 4; ++g)
            bf[g] = *(const short8*)(wp + (size_t)((s * 4 + g) * 64 + lane) * 8);
        #pragma unroll
        for (int mt = 0; mt < 2; ++mt)
            #pragma unroll
            for (int g = 0; g < 4; ++g)
                acc[mt][g] = __builtin_amdgcn_mfma_f32_16x16x32_bf16(A[mt][s], bf[g], acc[mt][g], 0, 0, 0);
    }

    // ---- epilogue: register run-compression over 4 consecutive sorted tasks
    float bs[4];
    #pragma unroll
    for (int g = 0; g < 4; ++g) bs[g] = bias[g * 16 + m16];
    float* outb = out + (size_t)b * MVERT * COUT;

    #pragma unroll
    for (int mt = 0; mt < 2; ++mt) {
        int   rr[4]; float vv[4]; bool val[4];
        #pragma unroll
        for (int r = 0; r < 4; ++r) {
            const int tsk = mt * 16 + quad * 4 + r;        // C row = quad*4 + reg
            rr[r]  = __shfl(rowv, tsk);
            vv[r]  = __shfl(valv, tsk);
            val[r] = (z0w + tsk) < NNZ;
        }
        bool emit[4];   // last element of an equal-row run
        #pragma unroll
        for (int r = 0; r < 4; ++r)
            emit[r] = (r == 3) || (!val[r + 1 > 3 ? 3 : r + 1]) || (rr[r + 1 > 3 ? 3 : r + 1] != rr[r]);
        #pragma unroll
        for (int g = 0; g < 4; ++g) {
            const int ch = g * 16 + m16;
            float s = 0.0f;
            #pragma unroll
            for (int r = 0; r < 4; ++r) {
                if (val[r]) {
                    float y = acc[mt][g][r] + bs[g];
                    y = (y > 0.0f) ? y : (__expf(y) - 1.0f);
                    s += y * vv[r];
                    if (emit[r]) {
                        atomicAdd(outb + (size_t)rr[r] * COUT + ch, s);
                        s = 0.0f;
                    }
                }
            }
        }
    }
}

extern "C" void kernel_launch(void* const* d_in, const int* in_sizes, int n_in,
                              void* d_out, int out_size, void* d_ws, size_t ws_size,
                              hipStream_t stream) {
    const float* x      = (const float*)d_in[0];
    const float* w      = (const float*)d_in[1];
    const float* bias   = (const float*)d_in[2];
    const float* vals   = (const float*)d_in[3];
    const int*   spiral = (const int*)d_in[4];
    const int*   rows   = (const int*)d_in[5];
    const int*   cols   = (const int*)d_in[6];
    float* out = (float*)d_out;

    // ws layout
    char* base = (char*)d_ws;
    unsigned short* wp     = (unsigned short*)(base);                    //    36,864 B
    unsigned short* x16    = (unsigned short*)(base + 36864);            // 25,600,000 B
    int*            hist   = (int*)(base + 25636864);
    int*            off2   = (int*)(base + 25686864);
    int*            rows_s = (int*)(base + 25736864);
    int*            barcnt = (int*)(base + 25900000);                    // in slack gap
    float*          vals_s = (float*)(base + 26036896);
    unsigned short* tidx   = (unsigned short*)(base + 26186912);         //  1,200,000 B

    const int prep_grid = PRE_BLOCKS + PACK_BLOCKS + ZERO_BLOCKS;
    prep_kernel<<<prep_grid, 256, 0, stream>>>(x, w, x16, wp, out, barcnt);
    sort_kernel<<<SORT_BLOCKS, 256, 0, stream>>>(rows, cols, vals, spiral,
                                                 hist, off2, rows_s, vals_s,
                                                 tidx, barcnt);
    spiral_mfma9_kernel<<<BATCH * TPB, 256, 0, stream>>>(x16, wp, bias, tidx,
                                                         rows_s, vals_s, out);
}

// Round 5
// 186.012 us; speedup vs baseline: 2.6418x; 1.0066x over previous
//
#include <hip/hip_runtime.h>

// Problem constants (fixed by the reference file)
#define BATCH   8
#define NVERT   50000
#define CIN     32
#define LSP     9
#define COUT    64
#define MVERT   12500
#define NNZ     37500

#define NFRAG   2304           // 9 s * 4 g * 64 lanes (B fragments)
#define OUTDW   (BATCH * MVERT * COUT)

#define TASKS_PB 64            // tasks per block (16 per wave, 1 M-tile)
#define BLK_B    586           // ceil(37500/64)

#define SORT_BLOCKS  49
#define SORT_THREADS (SORT_BLOCKS * 256)   // 12544 >= MVERT
#define PRE_BLOCKS   6250
#define PACK_BLOCKS  9
#define ZERO_BLOCKS  6250

typedef __attribute__((ext_vector_type(8))) short  short8;
typedef __attribute__((ext_vector_type(4))) float  floatx4;

static __device__ __forceinline__ unsigned short f2bf(float f) {
    union { float f; unsigned int u; } c; c.f = f;
    unsigned int u = c.u;
    return (unsigned short)((u + 0x7fffu + ((u >> 16) & 1u)) >> 16);
}

// scan partials (device globals; rewritten every replay before use)
__device__ int g_bsum[64];
__device__ int g_bsumP[64];

// software global barrier among the 49 sort blocks (co-resident by
// construction). Agent-scope acq/rel so plain stores made before the
// barrier are visible across XCDs after it. Proven correct in round 4.
static __device__ __forceinline__ void gbar(int* cnt, int target) {
    __syncthreads();
    if (threadIdx.x == 0) {
        __hip_atomic_fetch_add(cnt, 1, __ATOMIC_RELEASE, __HIP_MEMORY_SCOPE_AGENT);
        while (__hip_atomic_load(cnt, __ATOMIC_ACQUIRE, __HIP_MEMORY_SCOPE_AGENT) < target)
            __builtin_amdgcn_s_sleep(2);
    }
    __syncthreads();
}

// ---- k1 (fused): blocks 0..48 run the full sort pipeline (hist -> scan ->
// scatter, gbar-synced); blocks 49.. stream precast-x / pack-W / zero-out
// CONCURRENTLY (sort depends only on rows/cols/vals/spiral, prep only on
// x/w -> independent). Removes one dispatch boundary and hides the entire
// sort chain under the prep streaming time. hist+barcnt pre-zeroed by memset.
__global__ __launch_bounds__(256)
void prep_sort_kernel(const float* __restrict__ x, const float* __restrict__ w,
                      const int* __restrict__ rows, const int* __restrict__ cols,
                      const float* __restrict__ vals, const int* __restrict__ spiral,
                      unsigned short* __restrict__ x16, unsigned short* __restrict__ wp,
                      float* __restrict__ out,
                      int* __restrict__ hist, int* __restrict__ barcnt,
                      int* __restrict__ off2,
                      int* __restrict__ rows_s, float* __restrict__ vals_s,
                      unsigned short* __restrict__ tidx)
{
    const int blk = blockIdx.x;
    const int tid = threadIdx.x;

    if (blk < SORT_BLOCKS) {
        const int gid = blk * 256 + tid;

        // phase 1: histogram of rows (hist pre-zeroed by memset)
        for (int z = gid; z < NNZ; z += SORT_THREADS)
            atomicAdd(&hist[rows[z]], 1);
        gbar(barcnt, 1 * SORT_BLOCKS);

        // phase 2: block-local scan of 256 hist entries
        __shared__ int sh[256];
        {
            const int v = (gid < MVERT) ? hist[gid] : 0;
            sh[tid] = v;
            __syncthreads();
            #pragma unroll
            for (int d = 1; d < 256; d <<= 1) {
                int u = (tid >= d) ? sh[tid - d] : 0;
                __syncthreads();
                sh[tid] += u;
                __syncthreads();
            }
            const int incl = sh[tid];
            if (gid < MVERT) off2[gid] = incl - v;      // local exclusive
            if (tid == 255) g_bsum[blk] = incl;
        }
        gbar(barcnt, 2 * SORT_BLOCKS);

        // phase 3: scan the 49 block sums (serial, trivial)
        if (blk == 0 && tid == 0) {
            int run = 0;
            for (int k = 0; k < SORT_BLOCKS; ++k) {
                int t = g_bsum[k];
                g_bsumP[k] = run;
                run += t;
            }
        }
        gbar(barcnt, 3 * SORT_BLOCKS);

        // phase 4: add block prefix
        if (gid < MVERT) off2[gid] += g_bsumP[blk];
        gbar(barcnt, 4 * SORT_BLOCKS);

        // phase 5: scatter into row-sorted order + packed spiral indices
        for (int z = gid; z < NNZ; z += SORT_THREADS) {
            int r = rows[z];
            int c = cols[z];
            int pos = atomicAdd(&off2[r], 1);
            rows_s[pos] = r;
            vals_s[pos] = vals[z];
            unsigned short t[16];
            #pragma unroll
            for (int s = 0; s < 9; ++s) t[s] = (unsigned short)spiral[c * LSP + s];
            #pragma unroll
            for (int s = 9; s < 16; ++s) t[s] = 0;
            uint4* dst = (uint4*)(tidx + (size_t)pos * 16);
            dst[0] = *(uint4*)t;
            dst[1] = *(uint4*)(t + 8);
        }
        return;
    }

    const int pblk = blk - SORT_BLOCKS;
    if (pblk < PRE_BLOCKS) {
        const size_t base = ((size_t)pblk * 256 + tid) * 8;
        const float4* s = (const float4*)(x + base);
        float4 a = s[0], c = s[1];
        unsigned short t[8];
        t[0]=f2bf(a.x); t[1]=f2bf(a.y); t[2]=f2bf(a.z); t[3]=f2bf(a.w);
        t[4]=f2bf(c.x); t[5]=f2bf(c.y); t[6]=f2bf(c.z); t[7]=f2bf(c.w);
        *(uint4*)(x16 + base) = *(uint4*)t;
    } else if (pblk < PRE_BLOCKS + PACK_BLOCKS) {
        // B-frag f=(s*4+g)*64+lane holds W[s*32+(lane>>4)*8+j][g*16+(lane&15)]
        const int f = (pblk - PRE_BLOCKS) * 256 + tid;
        if (f < NFRAG) {
            int s = f >> 8, g = (f >> 6) & 3, lane = f & 63;
            int k0 = s * 32 + (lane >> 4) * 8, col = g * 16 + (lane & 15);
            unsigned short t[8];
            #pragma unroll
            for (int j = 0; j < 8; ++j)
                t[j] = f2bf(w[(size_t)(k0 + j) * COUT + col]);
            ((uint4*)wp)[f] = *(uint4*)t;
        }
    } else {
        const size_t base = ((size_t)(pblk - PRE_BLOCKS - PACK_BLOCKS) * 256 + tid) * 4;
        if (base < OUTDW) *(uint4*)(out + base) = (uint4){0, 0, 0, 0};
    }
}

// ---- k2: fused gather+GEMM+ELU+scale + register-aggregated scatter-add.
// Restructured 32 -> 16 tasks/wave (1 M-tile): A[9]=36 regs (was A[2][9]=72),
// acc[4]=16 (was 32) -> ~96 total regs/wave -> 5 waves/SIMD (20/CU, ~62% occ)
// vs the unavoidable 148-reg/3-wave allocation of the 2-M-tile version.
// Kernel is latency-bound (all pipes <16%, dur*occ ~ const across r0-r2),
// so resident waves are the throughput currency. Per-task gather/MFMA work
// unchanged; only wp B-loads double (shown non-critical in round 2).
__global__ __launch_bounds__(256, 5)
void spiral_mfma10_kernel(const unsigned short* __restrict__ x16,
                          const unsigned short* __restrict__ wp,
                          const float* __restrict__ bias,
                          const unsigned short* __restrict__ tidx,
                          const int* __restrict__ rows_s,
                          const float* __restrict__ vals_s,
                          float* __restrict__ out)
{
    const int bid  = blockIdx.x;
    const int b    = bid & 7;          // XCD swizzle: batch <-> XCD (x16/out L2-local)
    const int tile = bid >> 3;
    const int tid  = threadIdx.x;
    const int w    = tid >> 6;
    const int lane = tid & 63;
    const int quad = lane >> 4;
    const int m16  = lane & 15;
    const int z0w  = tile * TASKS_PB + 16 * w;   // wave's first sorted-task index

    // per-lane task metadata: lane L carries task z0w + (L&15)
    const int   zc   = min(z0w + m16, NNZ - 1);
    const int   rowv = rows_s[zc];
    const float valv = vals_s[zc];
    const uint4 p0 = *(const uint4*)(tidx + (size_t)zc * 16);
    const unsigned int p1 = *(const unsigned int*)(tidx + (size_t)zc * 16 + 8);
    int idx[9];
    idx[0] = p0.x & 0xffff;  idx[1] = p0.x >> 16;
    idx[2] = p0.y & 0xffff;  idx[3] = p0.y >> 16;
    idx[4] = p0.z & 0xffff;  idx[5] = p0.z >> 16;
    idx[6] = p0.w & 0xffff;  idx[7] = p0.w >> 16;
    idx[8] = p1 & 0xffff;

    const unsigned short* xb = x16 + (size_t)b * NVERT * CIN;

    // ---- all 9 A-fragment gathers up front: one latency round-trip
    short8 A[9];
    #pragma unroll
    for (int s = 0; s < 9; ++s) {
        int tix = __shfl(idx[s], m16);
        A[s] = *(const short8*)(xb + (size_t)tix * CIN + quad * 8);
    }

    floatx4 acc[4];
    #pragma unroll
    for (int g = 0; g < 4; ++g) acc[g] = (floatx4){0.f, 0.f, 0.f, 0.f};

    #pragma unroll
    for (int s = 0; s < 9; ++s) {
        short8 bf[4];
        #pragma unroll
        for (int g = 0; g < 4; ++g)
            bf[g] = *(const short8*)(wp + (size_t)((s * 4 + g) * 64 + lane) * 8);
        #pragma unroll
        for (int g = 0; g < 4; ++g)
            acc[g] = __builtin_amdgcn_mfma_f32_16x16x32_bf16(A[s], bf[g], acc[g], 0, 0, 0);
    }

    // ---- epilogue: register run-compression over 4 consecutive sorted tasks
    float bs[4];
    #pragma unroll
    for (int g = 0; g < 4; ++g) bs[g] = bias[g * 16 + m16];
    float* outb = out + (size_t)b * MVERT * COUT;

    int   rr[4]; float vv[4]; bool val[4];
    #pragma unroll
    for (int r = 0; r < 4; ++r) {
        const int tsk = quad * 4 + r;              // C row = quad*4 + reg
        rr[r]  = __shfl(rowv, tsk);
        vv[r]  = __shfl(valv, tsk);
        val[r] = (z0w + tsk) < NNZ;
    }
    bool emit[4];   // last element of an equal-row run
    #pragma unroll
    for (int r = 0; r < 4; ++r)
        emit[r] = (r == 3) || (!val[r + 1 > 3 ? 3 : r + 1]) || (rr[r + 1 > 3 ? 3 : r + 1] != rr[r]);
    #pragma unroll
    for (int g = 0; g < 4; ++g) {
        const int ch = g * 16 + m16;
        float s = 0.0f;
        #pragma unroll
        for (int r = 0; r < 4; ++r) {
            if (val[r]) {
                float y = acc[g][r] + bs[g];
                y = (y > 0.0f) ? y : (__expf(y) - 1.0f);
                s += y * vv[r];
                if (emit[r]) {
                    atomicAdd(outb + (size_t)rr[r] * COUT + ch, s);
                    s = 0.0f;
                }
            }
        }
    }
}

extern "C" void kernel_launch(void* const* d_in, const int* in_sizes, int n_in,
                              void* d_out, int out_size, void* d_ws, size_t ws_size,
                              hipStream_t stream) {
    const float* x      = (const float*)d_in[0];
    const float* w      = (const float*)d_in[1];
    const float* bias   = (const float*)d_in[2];
    const float* vals   = (const float*)d_in[3];
    const int*   spiral = (const int*)d_in[4];
    const int*   rows   = (const int*)d_in[5];
    const int*   cols   = (const int*)d_in[6];
    float* out = (float*)d_out;

    // ws layout (hist and barcnt contiguous -> one memset zeroes both)
    char* base = (char*)d_ws;
    unsigned short* wp     = (unsigned short*)(base);                    //    36,864 B
    unsigned short* x16    = (unsigned short*)(base + 36864);            // 25,600,000 B
    int*            hist   = (int*)(base + 25636864);                    //     50,000 B
    int*            barcnt = (int*)(base + 25686864);                    //         16 B
    int*            off2   = (int*)(base + 25686880);                    //     50,000 B
    int*            rows_s = (int*)(base + 25736880);                    //    150,000 B
    float*          vals_s = (float*)(base + 25886880);                  //    150,000 B
    unsigned short* tidx   = (unsigned short*)(base + 26186912);         //  1,200,000 B

    hipMemsetAsync(hist, 0, MVERT * sizeof(int) + 16, stream);   // hist + barcnt

    const int fused_grid = SORT_BLOCKS + PRE_BLOCKS + PACK_BLOCKS + ZERO_BLOCKS;
    prep_sort_kernel<<<fused_grid, 256, 0, stream>>>(x, w, rows, cols, vals,
                                                     spiral, x16, wp, out,
                                                     hist, barcnt, off2,
                                                     rows_s, vals_s, tidx);
    spiral_mfma10_kernel<<<BATCH * BLK_B, 256, 0, stream>>>(x16, wp, bias, tidx,
                                                            rows_s, vals_s, out);
}